// Round 4
// baseline (1753.401 us; speedup 1.0000x reference)
//
#include <hip/hip_runtime.h>

using f32x4  = __attribute__((ext_vector_type(4))) float;
using short8 = __attribute__((ext_vector_type(8))) short;
using u32x4  = __attribute__((ext_vector_type(4))) unsigned int;

#define DEV __device__ __forceinline__
#define MFMA16(a, b, c) __builtin_amdgcn_mfma_f32_16x16x32_bf16(a, b, c, 0, 0, 0)

// B=32, CIN=1, NBINS=128, NFRAMES=256, NFILT=64 -> Hc=64, Wc=128
// context: [2048][8192] (row m = b*64+l, col f = c*128+w)
// DDEC=512, G=1536, T=64, NCLS=17, NWG=32
// ctxW layout: [b][n][l] = [32][1536][64] f32

DEV unsigned short f2bf(float f) {
  unsigned int u = __float_as_uint(f);
  unsigned int r = (u + 0x7fffu + ((u >> 16) & 1u)) >> 16;
  return (unsigned short)r;
}
DEV float bf2f(unsigned short s) { return __uint_as_float(((unsigned int)s) << 16); }
DEV float sigm(float x) { return 1.0f / (1.0f + expf(-x)); }

// ---------------- K1: prep (split weights, zero scan state) ---------------------
__global__ __launch_bounds__(256) void k_prep(
    const float* __restrict__ wih, const float* __restrict__ whh,
    unsigned short* __restrict__ wih_hi, unsigned short* __restrict__ wih_lo,
    unsigned short* __restrict__ whh_hi, unsigned short* __restrict__ whh_lo,
    unsigned int* __restrict__ hbuf, int* __restrict__ flags) {
  unsigned int i = blockIdx.x * 256u + threadIdx.x;
  if (i < 12582912u) {
    float w = wih[i];
    unsigned short h = f2bf(w);
    wih_hi[i] = h;
    wih_lo[i] = f2bf(w - bf2f(h));
  }
  if (i < 786432u) {
    float w = whh[i];
    unsigned short h = f2bf(w);
    whh_hi[i] = h;
    whh_lo[i] = f2bf(w - bf2f(h));
  }
  if (i < 32768u) hbuf[i] = 0u;
  if (i < 512u) flags[i] = 0;
}

// ---------------- K2: conv 3x3 stride2 pad1 -> context (bf16 hi/lo) --------------
__global__ __launch_bounds__(128) void k_conv(
    const float* __restrict__ x, const float* __restrict__ cw,
    unsigned short* __restrict__ ctx_hi, unsigned short* __restrict__ ctx_lo) {
  __shared__ float w[576];
  int t = threadIdx.x;
  for (int i = t; i < 576; i += 128) w[i] = cw[i];
  int blk = blockIdx.x;  // b*64 + h
  int b = blk >> 6, h = blk & 63;
  const float* xb = x + (size_t)b * 32768;
  int wcol = t;
  float xv[3][3];
  int ih0 = 2 * h - 1, iw0 = 2 * wcol - 1;
#pragma unroll
  for (int kh = 0; kh < 3; kh++) {
    int ih = ih0 + kh;
#pragma unroll
    for (int kw = 0; kw < 3; kw++) {
      int iw = iw0 + kw;
      bool ok = (ih >= 0) && (ih < 128) && (iw >= 0) && (iw < 256);
      xv[kh][kw] = ok ? xb[ih * 256 + iw] : 0.f;
    }
  }
  __syncthreads();
  size_t base = (size_t)blk * 8192 + wcol;
  for (int c = 0; c < 64; c++) {
    const float* wc = &w[c * 9];
    float acc = 0.f;
#pragma unroll
    for (int kh = 0; kh < 3; kh++)
#pragma unroll
      for (int kw = 0; kw < 3; kw++) acc += xv[kh][kw] * wc[kh * 3 + kw];
    unsigned short hi = f2bf(acc);
    ctx_hi[base + c * 128] = hi;
    ctx_lo[base + c * 128] = f2bf(acc - bf2f(hi));
  }
}

// ---------------- K3: ctxW = context @ W_ih^T  (split-bf16, 3-term MFMA) ---------
__global__ __launch_bounds__(256) void k_gemm(
    const unsigned short* __restrict__ A_hi, const unsigned short* __restrict__ A_lo,
    const unsigned short* __restrict__ B_hi, const unsigned short* __restrict__ B_lo,
    float* __restrict__ ctxW) {
  __shared__ unsigned short Ah[128 * 32], Al[128 * 32], Bh[128 * 32], Bl[128 * 32];
  int tid = threadIdx.x;
  int m0 = blockIdx.x * 128, n0 = blockIdx.y * 128;
  int wave = tid >> 6, lane = tid & 63;
  int wm = wave >> 1, wn = wave & 1;
  const f32x4 zero4 = {0.f, 0.f, 0.f, 0.f};
  f32x4 acc[4][4];
  for (int mi = 0; mi < 4; mi++)
    for (int ni = 0; ni < 4; ni++) acc[mi][ni] = zero4;

  for (int k0 = 0; k0 < 8192; k0 += 32) {
    __syncthreads();
#pragma unroll
    for (int i = 0; i < 2; i++) {
      int c = tid + i * 256;
      int row = c >> 2, col = (c & 3) << 3;
      size_t ga = (size_t)(m0 + row) * 8192 + k0 + col;
      size_t gb = (size_t)(n0 + row) * 8192 + k0 + col;
      *(short8*)&Ah[row * 32 + col] = *(const short8*)&A_hi[ga];
      *(short8*)&Al[row * 32 + col] = *(const short8*)&A_lo[ga];
      *(short8*)&Bh[row * 32 + col] = *(const short8*)&B_hi[gb];
      *(short8*)&Bl[row * 32 + col] = *(const short8*)&B_lo[gb];
    }
    __syncthreads();
    int kc = (lane >> 4) * 8;
    short8 ah[4], al[4], bh[4], bl[4];
#pragma unroll
    for (int mi = 0; mi < 4; mi++) {
      int r = wm * 64 + mi * 16 + (lane & 15);
      ah[mi] = *(short8*)&Ah[r * 32 + kc];
      al[mi] = *(short8*)&Al[r * 32 + kc];
    }
#pragma unroll
    for (int ni = 0; ni < 4; ni++) {
      int r = wn * 64 + ni * 16 + (lane & 15);
      bh[ni] = *(short8*)&Bh[r * 32 + kc];
      bl[ni] = *(short8*)&Bl[r * 32 + kc];
    }
#pragma unroll
    for (int mi = 0; mi < 4; mi++)
#pragma unroll
      for (int ni = 0; ni < 4; ni++) {
        acc[mi][ni] = MFMA16(ah[mi], bh[ni], acc[mi][ni]);
        acc[mi][ni] = MFMA16(ah[mi], bl[ni], acc[mi][ni]);
        acc[mi][ni] = MFMA16(al[mi], bh[ni], acc[mi][ni]);
      }
  }
  // epilogue: ctxW[b][n][l], 4 consecutive l per f32x4 accumulator
#pragma unroll
  for (int mi = 0; mi < 4; mi++)
#pragma unroll
    for (int ni = 0; ni < 4; ni++) {
      int n = n0 + wn * 64 + ni * 16 + (lane & 15);
      int mb = m0 + wm * 64 + mi * 16 + (lane >> 4) * 4;
      int bb = mb >> 6, l = mb & 63;
      *(f32x4*)&ctxW[(size_t)(bb * 1536 + n) * 64 + l] = acc[mi][ni];
    }
}

// ---------------- K4: scan — 32 wgs, flag sync, fused stage+kappa/beta -----------
#define NWG 32

__global__ __launch_bounds__(512) void k_scan(
    const float* __restrict__ ctxW,
    const unsigned short* __restrict__ whh_hi, const unsigned short* __restrict__ whh_lo,
    const float* __restrict__ kw, const float* __restrict__ bw,
    const float* __restrict__ ow,
    unsigned int* __restrict__ hbuf, int* __restrict__ flags,
    float* __restrict__ pout, float* __restrict__ d_out) {
  __shared__ unsigned int h_lds[32 * 512];  // packed hi<<16|lo, 16B-XOR-swizzled
  __shared__ float ws_lds[32][64];
  __shared__ float gh_lds[32][48];
  __shared__ float hnew_lds[32][16];
  __shared__ float kwb[512], bwb[512];
  __shared__ float kappa_l[32], beta_l[32];

  const int g = blockIdx.x;
  const int tid = threadIdx.x;
  const int b = tid >> 4, jj = tid & 15;
  const int wave = tid >> 6, lane = tid & 63;
  const int j0 = g * 16;
  float h_prev = 0.f;

  kwb[tid] = kw[tid];
  bwb[tid] = bw[tid];
  if (tid < 32) kappa_l[tid] = 0.f;
  __syncthreads();

  for (int t = 0; t < 64; t++) {
    // ---- wait for all wgs to have published step t-1 (padded flags) ----
    if (t > 0) {
      if (tid < 32) {
        while (__hip_atomic_load(&flags[tid * 16], __ATOMIC_ACQUIRE,
                                 __HIP_MEMORY_SCOPE_AGENT) < t)
          __builtin_amdgcn_s_sleep(1);
      }
      __syncthreads();
    }
    // ---- Phase A: stage h -> LDS, fused kappa/beta dot (redundant per wg) ----
    {
      const unsigned long long* hs =
          (const unsigned long long*)(hbuf + (t & 1) * 16384);
      float kd = 0.f, bd = 0.f;
#pragma unroll
      for (int q = 0; q < 16; q++) {
        int m = b * 256 + jj + q * 16;  // u64 index within row b, coalesced
        unsigned long long v = __hip_atomic_load(&hs[m], __ATOMIC_RELAXED,
                                                 __HIP_MEMORY_SCOPE_AGENT);
        int ob = (jj + q * 16) * 8;
        *(unsigned long long*)((char*)h_lds + b * 2048 +
                               (ob ^ ((b & 7) << 4))) = v;
        unsigned int u0 = (unsigned int)v;
        unsigned int u1 = (unsigned int)(v >> 32);
        float h0 = __uint_as_float(u0 & 0xffff0000u) + __uint_as_float(u0 << 16);
        float h1 = __uint_as_float(u1 & 0xffff0000u) + __uint_as_float(u1 << 16);
        int j = (jj + q * 16) * 2;
        kd = fmaf(h0, kwb[j], fmaf(h1, kwb[j + 1], kd));
        bd = fmaf(h0, bwb[j], fmaf(h1, bwb[j + 1], bd));
      }
#pragma unroll
      for (int mm = 1; mm < 16; mm <<= 1) {
        kd += __shfl_xor(kd, mm, 64);
        bd += __shfl_xor(bd, mm, 64);
      }
      if (jj == 0) {
        kappa_l[b] += kd;
        beta_l[b] = expf(bd);
      }
    }
    __syncthreads();
    // ---- Phase B: attention weights ----
#pragma unroll
    for (int p = 0; p < 4; p++) {
      int i = tid + p * 512;
      int bb = i >> 6, l = i & 63;
      float d = kappa_l[bb] - (float)l;
      float wv = expf(-beta_l[bb] * d * d);
      ws_lds[bb][l] = wv;
      if (bb == g) d_out[34816 + ((bb << 6) + t) * 64 + l] = wv;
    }
    __syncthreads();
    // ---- Phase C: gh MFMA (waves 0..5); waves 6-7 fall through to gx ----
    if (wave < 6) {
      int mt = wave & 1, nt = wave >> 1;
      int ar = mt * 16 + (lane & 15);                // batch row
      int n_g = nt * 512 + j0 + (lane & 15);         // global gate-row
      int sw = (ar & 7) << 4;
      const char* arow_p = (const char*)h_lds + ar * 2048;
      f32x4 acc = {0.f, 0.f, 0.f, 0.f};
      for (int ks = 0; ks < 16; ks++) {
        int ob = ks * 128 + (lane >> 4) * 32;
        u32x4 v1 = *(const u32x4*)(arow_p + (ob ^ sw));
        u32x4 v2 = *(const u32x4*)(arow_p + ((ob + 16) ^ sw));
        short8 ah, al;
#pragma unroll
        for (int q = 0; q < 4; q++) {
          ah[q] = (short)(v1[q] >> 16);
          al[q] = (short)(v1[q] & 0xffffu);
          ah[4 + q] = (short)(v2[q] >> 16);
          al[4 + q] = (short)(v2[q] & 0xffffu);
        }
        int kc = ks * 32 + (lane >> 4) * 8;
        short8 bh = *(const short8*)&whh_hi[(size_t)n_g * 512 + kc];
        short8 bl = *(const short8*)&whh_lo[(size_t)n_g * 512 + kc];
        acc = MFMA16(ah, bh, acc);
        acc = MFMA16(ah, bl, acc);
        acc = MFMA16(al, bh, acc);
      }
#pragma unroll
      for (int r = 0; r < 4; r++)
        gh_lds[mt * 16 + (lane >> 4) * 4 + r][nt * 16 + (lane & 15)] = acc[r];
    }
    // ---- Phase D: gx from ctxW[b][n][l], vectorized f32x4 over l ----
    float gx0 = 0.f, gx1 = 0.f, gx2 = 0.f;
    {
      const float* cb = ctxW + (size_t)(b * 1536 + j0 + jj) * 64;
#pragma unroll
      for (int lc = 0; lc < 16; lc++) {
        f32x4 w4 = *(const f32x4*)&ws_lds[b][lc * 4];
        f32x4 c0 = *(const f32x4*)(cb + lc * 4);
        f32x4 c1 = *(const f32x4*)(cb + 32768 + lc * 4);
        f32x4 c2 = *(const f32x4*)(cb + 65536 + lc * 4);
#pragma unroll
        for (int q = 0; q < 4; q++) {
          gx0 = fmaf(w4[q], c0[q], gx0);
          gx1 = fmaf(w4[q], c1[q], gx1);
          gx2 = fmaf(w4[q], c2[q], gx2);
        }
      }
    }
    __syncthreads();
    // ---- Phase E: gates + hidden update + publish h ----
    {
      float rr = sigm(gx0 + gh_lds[b][jj]);
      float zz = sigm(gx1 + gh_lds[b][16 + jj]);
      float nn = tanhf(gx2 + rr * gh_lds[b][32 + jj]);
      float h = (1.f - zz) * nn + zz * h_prev;
      h_prev = h;
      hnew_lds[b][jj] = h;
      unsigned short hh = f2bf(h);
      unsigned short hl = f2bf(h - bf2f(hh));
      __hip_atomic_store(&hbuf[((t + 1) & 1) * 16384 + b * 512 + j0 + jj],
                         ((unsigned int)hh << 16) | (unsigned int)hl,
                         __ATOMIC_RELAXED, __HIP_MEMORY_SCOPE_AGENT);
    }
    __syncthreads();
    // ---- publish step-t completion (hbuf stores drained by barrier) ----
    if (tid == 0)
      __hip_atomic_store(&flags[g * 16], t + 1, __ATOMIC_RELEASE,
                         __HIP_MEMORY_SCOPE_AGENT);
    // ---- Phase F: out-projection partials (strided: 544 items, 512 threads) ----
    for (int i = tid; i < 544; i += 512) {
      int bo = i / 17, k = i - bo * 17;
      const float* owr = ow + k * 512 + j0;
      float s = 0.f;
#pragma unroll
      for (int j = 0; j < 16; j++) s += hnew_lds[bo][j] * owr[j];
      pout[((t * 32 + g) * 32 + bo) * 17 + k] = s;
    }
  }
}

// ---------------- K5: reduce pout over wgs + bias -> d_out ----------------------
__global__ __launch_bounds__(256) void k_fin(
    const float* __restrict__ pout, const float* __restrict__ ob,
    float* __restrict__ d_out) {
  int i = blockIdx.x * 256 + threadIdx.x;
  if (i >= 34816) return;
  int k = i % 17;
  int bt = i / 17;
  int b = bt >> 6, t = bt & 63;
  float s = ob[k];
#pragma unroll 8
  for (int g = 0; g < 32; g++) s += pout[((t * 32 + g) * 32 + b) * 17 + k];
  d_out[i] = s;
}

// ---------------- launch ----------------
extern "C" void kernel_launch(void* const* d_in, const int* in_sizes, int n_in,
                              void* d_out, int out_size, void* d_ws, size_t ws_size,
                              hipStream_t stream) {
  (void)in_sizes; (void)n_in; (void)out_size; (void)ws_size;
  const float* x   = (const float*)d_in[0];
  const float* cw  = (const float*)d_in[2];
  const float* kw  = (const float*)d_in[3];
  const float* bw  = (const float*)d_in[4];
  const float* wih = (const float*)d_in[5];
  const float* whh = (const float*)d_in[6];
  const float* ow  = (const float*)d_in[7];
  const float* ob  = (const float*)d_in[8];
  float* out = (float*)d_out;
  char* ws = (char*)d_ws;

  unsigned short* ctx_hi = (unsigned short*)(ws);
  unsigned short* ctx_lo = (unsigned short*)(ws + 33554432);
  unsigned short* wih_hi = (unsigned short*)(ws + 67108864);
  unsigned short* wih_lo = (unsigned short*)(ws + 92274688);
  unsigned short* whh_hi = (unsigned short*)(ws + 117440512);
  unsigned short* whh_lo = (unsigned short*)(ws + 119013376);
  float*          ctxW   = (float*)(ws + 120586240);  // [32][1536][64]
  unsigned int*   hbuf   = (unsigned int*)(ws + 133169152);
  int*            flags  = (int*)(ws + 133300224);    // [32*16] padded
  float*          pout   = (float*)(ws);              // overlay ctx_hi (dead after k_gemm)

  k_prep<<<49152, 256, 0, stream>>>(wih, whh, wih_hi, wih_lo, whh_hi, whh_lo,
                                    hbuf, flags);
  k_conv<<<2048, 128, 0, stream>>>(x, cw, ctx_hi, ctx_lo);
  k_gemm<<<dim3(16, 12), 256, 0, stream>>>(ctx_hi, ctx_lo, wih_hi, wih_lo, ctxW);
  k_scan<<<NWG, 512, 0, stream>>>(ctxW, whh_hi, whh_lo, kw, bw, ow,
                                  hbuf, flags, pout, out);
  k_fin<<<136, 256, 0, stream>>>(pout, ob, out);
}

// Round 5
// 1635.022 us; speedup vs baseline: 1.0724x; 1.0724x over previous
//
#include <hip/hip_runtime.h>

using f32x4  = __attribute__((ext_vector_type(4))) float;
using short8 = __attribute__((ext_vector_type(8))) short;
using u32x4  = __attribute__((ext_vector_type(4))) unsigned int;

#define DEV __device__ __forceinline__
#define MFMA16(a, b, c) __builtin_amdgcn_mfma_f32_16x16x32_bf16(a, b, c, 0, 0, 0)

// B=32, CIN=1, NBINS=128, NFRAMES=256, NFILT=64 -> Hc=64, Wc=128
// context: [2048][8192] (row m = b*64+l, col f = c*128+w)
// DDEC=512, G=1536, T=64, NCLS=17, NWG=32
// ctxW layout: [b][n][l] = [32][1536][64] f32
// hbuf: [2][32][512] u64, word = (tag<<32)|((hi16<<16)|lo16); tag = step of h-state

DEV unsigned short f2bf(float f) {
  unsigned int u = __float_as_uint(f);
  unsigned int r = (u + 0x7fffu + ((u >> 16) & 1u)) >> 16;
  return (unsigned short)r;
}
DEV float bf2f(unsigned short s) { return __uint_as_float(((unsigned int)s) << 16); }
DEV float sigm(float x) { return 1.0f / (1.0f + expf(-x)); }

// ---------------- K1: prep (split weights, zero scan state) ---------------------
__global__ __launch_bounds__(256) void k_prep(
    const float* __restrict__ wih, const float* __restrict__ whh,
    unsigned short* __restrict__ wih_hi, unsigned short* __restrict__ wih_lo,
    unsigned short* __restrict__ whh_hi, unsigned short* __restrict__ whh_lo,
    unsigned long long* __restrict__ hbuf) {
  unsigned int i = blockIdx.x * 256u + threadIdx.x;
  if (i < 12582912u) {
    float w = wih[i];
    unsigned short h = f2bf(w);
    wih_hi[i] = h;
    wih_lo[i] = f2bf(w - bf2f(h));
  }
  if (i < 786432u) {
    float w = whh[i];
    unsigned short h = f2bf(w);
    whh_hi[i] = h;
    whh_lo[i] = f2bf(w - bf2f(h));
  }
  if (i < 32768u) hbuf[i] = 0ull;  // tag 0, payload 0 == h0 state
}

// ---------------- K2: conv 3x3 stride2 pad1 -> context (bf16 hi/lo) --------------
__global__ __launch_bounds__(128) void k_conv(
    const float* __restrict__ x, const float* __restrict__ cw,
    unsigned short* __restrict__ ctx_hi, unsigned short* __restrict__ ctx_lo) {
  __shared__ float w[576];
  int t = threadIdx.x;
  for (int i = t; i < 576; i += 128) w[i] = cw[i];
  int blk = blockIdx.x;  // b*64 + h
  int b = blk >> 6, h = blk & 63;
  const float* xb = x + (size_t)b * 32768;
  int wcol = t;
  float xv[3][3];
  int ih0 = 2 * h - 1, iw0 = 2 * wcol - 1;
#pragma unroll
  for (int kh = 0; kh < 3; kh++) {
    int ih = ih0 + kh;
#pragma unroll
    for (int kw = 0; kw < 3; kw++) {
      int iw = iw0 + kw;
      bool ok = (ih >= 0) && (ih < 128) && (iw >= 0) && (iw < 256);
      xv[kh][kw] = ok ? xb[ih * 256 + iw] : 0.f;
    }
  }
  __syncthreads();
  size_t base = (size_t)blk * 8192 + wcol;
  for (int c = 0; c < 64; c++) {
    const float* wc = &w[c * 9];
    float acc = 0.f;
#pragma unroll
    for (int kh = 0; kh < 3; kh++)
#pragma unroll
      for (int kw = 0; kw < 3; kw++) acc += xv[kh][kw] * wc[kh * 3 + kw];
    unsigned short hi = f2bf(acc);
    ctx_hi[base + c * 128] = hi;
    ctx_lo[base + c * 128] = f2bf(acc - bf2f(hi));
  }
}

// ---------------- K3: ctxW = context @ W_ih^T  (split-bf16, 3-term MFMA) ---------
__global__ __launch_bounds__(256) void k_gemm(
    const unsigned short* __restrict__ A_hi, const unsigned short* __restrict__ A_lo,
    const unsigned short* __restrict__ B_hi, const unsigned short* __restrict__ B_lo,
    float* __restrict__ ctxW) {
  __shared__ unsigned short Ah[128 * 32], Al[128 * 32], Bh[128 * 32], Bl[128 * 32];
  int tid = threadIdx.x;
  int m0 = blockIdx.x * 128, n0 = blockIdx.y * 128;
  int wave = tid >> 6, lane = tid & 63;
  int wm = wave >> 1, wn = wave & 1;
  const f32x4 zero4 = {0.f, 0.f, 0.f, 0.f};
  f32x4 acc[4][4];
  for (int mi = 0; mi < 4; mi++)
    for (int ni = 0; ni < 4; ni++) acc[mi][ni] = zero4;

  for (int k0 = 0; k0 < 8192; k0 += 32) {
    __syncthreads();
#pragma unroll
    for (int i = 0; i < 2; i++) {
      int c = tid + i * 256;
      int row = c >> 2, col = (c & 3) << 3;
      size_t ga = (size_t)(m0 + row) * 8192 + k0 + col;
      size_t gb = (size_t)(n0 + row) * 8192 + k0 + col;
      *(short8*)&Ah[row * 32 + col] = *(const short8*)&A_hi[ga];
      *(short8*)&Al[row * 32 + col] = *(const short8*)&A_lo[ga];
      *(short8*)&Bh[row * 32 + col] = *(const short8*)&B_hi[gb];
      *(short8*)&Bl[row * 32 + col] = *(const short8*)&B_lo[gb];
    }
    __syncthreads();
    int kc = (lane >> 4) * 8;
    short8 ah[4], al[4], bh[4], bl[4];
#pragma unroll
    for (int mi = 0; mi < 4; mi++) {
      int r = wm * 64 + mi * 16 + (lane & 15);
      ah[mi] = *(short8*)&Ah[r * 32 + kc];
      al[mi] = *(short8*)&Al[r * 32 + kc];
    }
#pragma unroll
    for (int ni = 0; ni < 4; ni++) {
      int r = wn * 64 + ni * 16 + (lane & 15);
      bh[ni] = *(short8*)&Bh[r * 32 + kc];
      bl[ni] = *(short8*)&Bl[r * 32 + kc];
    }
#pragma unroll
    for (int mi = 0; mi < 4; mi++)
#pragma unroll
      for (int ni = 0; ni < 4; ni++) {
        acc[mi][ni] = MFMA16(ah[mi], bh[ni], acc[mi][ni]);
        acc[mi][ni] = MFMA16(ah[mi], bl[ni], acc[mi][ni]);
        acc[mi][ni] = MFMA16(al[mi], bh[ni], acc[mi][ni]);
      }
  }
  // epilogue: ctxW[b][n][l], 4 consecutive l per f32x4 accumulator
#pragma unroll
  for (int mi = 0; mi < 4; mi++)
#pragma unroll
    for (int ni = 0; ni < 4; ni++) {
      int n = n0 + wn * 64 + ni * 16 + (lane & 15);
      int mb = m0 + wm * 64 + mi * 16 + (lane >> 4) * 4;
      int bb = mb >> 6, l = mb & 63;
      *(f32x4*)&ctxW[(size_t)(bb * 1536 + n) * 64 + l] = acc[mi][ni];
    }
}

// ---------------- K4: scan — 32 wgs, tagged-word sync (no fences, no flags) ------
#define NWG 32

__global__ __launch_bounds__(512) void k_scan(
    const float* __restrict__ ctxW,
    const unsigned short* __restrict__ whh_hi, const unsigned short* __restrict__ whh_lo,
    const float* __restrict__ kw, const float* __restrict__ bw,
    const float* __restrict__ ow,
    unsigned long long* __restrict__ hbuf,
    float* __restrict__ pout, float* __restrict__ d_out) {
  __shared__ unsigned int h_lds[32 * 512];  // payload u32, 16B-XOR-swizzled rows
  __shared__ float ws_lds[32][64];
  __shared__ float gh_lds[32][48];
  __shared__ float hnew_lds[32][16];
  __shared__ float kwb[512], bwb[512];
  __shared__ float kappa_l[32], beta_l[32];

  const int g = blockIdx.x;
  const int tid = threadIdx.x;
  const int b = tid >> 4, jj = tid & 15;
  const int wave = tid >> 6, lane = tid & 63;
  const int j0 = g * 16;
  float h_prev = 0.f;

  kwb[tid] = kw[tid];
  bwb[tid] = bw[tid];
  if (tid < 32) kappa_l[tid] = 0.f;
  __syncthreads();

  for (int t = 0; t < 64; t++) {
    // ---- Phase A: tag-validated h load (batched, pipelined) + fused kappa/beta --
    {
      const unsigned long long* hs = hbuf + (t & 1) * 16384;
      unsigned long long v[32];
#pragma unroll
      for (int q = 0; q < 32; q++)
        v[q] = __hip_atomic_load(&hs[b * 512 + jj + q * 16], __ATOMIC_RELAXED,
                                 __HIP_MEMORY_SCOPE_AGENT);
      float kd = 0.f, bd = 0.f;
#pragma unroll
      for (int q = 0; q < 32; q++) {
        while ((unsigned int)(v[q] >> 32) != (unsigned int)t) {
          __builtin_amdgcn_s_sleep(1);
          v[q] = __hip_atomic_load(&hs[b * 512 + jj + q * 16], __ATOMIC_RELAXED,
                                   __HIP_MEMORY_SCOPE_AGENT);
        }
        unsigned int u = (unsigned int)v[q];
        int j = jj + q * 16;
        *(unsigned int*)((char*)h_lds + b * 2048 + ((j * 4) ^ ((b & 7) << 4))) = u;
        float h0 = __uint_as_float(u & 0xffff0000u) + __uint_as_float(u << 16);
        kd = fmaf(h0, kwb[j], kd);
        bd = fmaf(h0, bwb[j], bd);
      }
#pragma unroll
      for (int mm = 1; mm < 16; mm <<= 1) {
        kd += __shfl_xor(kd, mm, 64);
        bd += __shfl_xor(bd, mm, 64);
      }
      if (jj == 0) {
        kappa_l[b] += kd;
        beta_l[b] = expf(bd);
      }
    }
    __syncthreads();
    // ---- Phase B: attention weights ----
#pragma unroll
    for (int p = 0; p < 4; p++) {
      int i = tid + p * 512;
      int bb = i >> 6, l = i & 63;
      float d = kappa_l[bb] - (float)l;
      float wv = expf(-beta_l[bb] * d * d);
      ws_lds[bb][l] = wv;
      if (bb == g) d_out[34816 + ((bb << 6) + t) * 64 + l] = wv;
    }
    __syncthreads();
    // ---- Phase C: gh MFMA (waves 0..5); waves 6-7 fall through to gx ----
    if (wave < 6) {
      int mt = wave & 1, nt = wave >> 1;
      int ar = mt * 16 + (lane & 15);                // batch row
      int n_g = nt * 512 + j0 + (lane & 15);         // global gate-row
      int sw = (ar & 7) << 4;
      const char* arow_p = (const char*)h_lds + ar * 2048;
      f32x4 acc = {0.f, 0.f, 0.f, 0.f};
      for (int ks = 0; ks < 16; ks++) {
        int ob = ks * 128 + (lane >> 4) * 32;
        u32x4 v1 = *(const u32x4*)(arow_p + (ob ^ sw));
        u32x4 v2 = *(const u32x4*)(arow_p + ((ob + 16) ^ sw));
        short8 ah, al;
#pragma unroll
        for (int q = 0; q < 4; q++) {
          ah[q] = (short)(v1[q] >> 16);
          al[q] = (short)(v1[q] & 0xffffu);
          ah[4 + q] = (short)(v2[q] >> 16);
          al[4 + q] = (short)(v2[q] & 0xffffu);
        }
        int kc = ks * 32 + (lane >> 4) * 8;
        short8 bh = *(const short8*)&whh_hi[(size_t)n_g * 512 + kc];
        short8 bl = *(const short8*)&whh_lo[(size_t)n_g * 512 + kc];
        acc = MFMA16(ah, bh, acc);
        acc = MFMA16(ah, bl, acc);
        acc = MFMA16(al, bh, acc);
      }
#pragma unroll
      for (int r = 0; r < 4; r++)
        gh_lds[mt * 16 + (lane >> 4) * 4 + r][nt * 16 + (lane & 15)] = acc[r];
    }
    // ---- Phase D: gx from ctxW[b][n][l], vectorized f32x4 over l ----
    float gx0 = 0.f, gx1 = 0.f, gx2 = 0.f;
    {
      const float* cb = ctxW + (size_t)(b * 1536 + j0 + jj) * 64;
#pragma unroll
      for (int lc = 0; lc < 16; lc++) {
        f32x4 w4 = *(const f32x4*)&ws_lds[b][lc * 4];
        f32x4 c0 = *(const f32x4*)(cb + lc * 4);
        f32x4 c1 = *(const f32x4*)(cb + 32768 + lc * 4);
        f32x4 c2 = *(const f32x4*)(cb + 65536 + lc * 4);
#pragma unroll
        for (int q = 0; q < 4; q++) {
          gx0 = fmaf(w4[q], c0[q], gx0);
          gx1 = fmaf(w4[q], c1[q], gx1);
          gx2 = fmaf(w4[q], c2[q], gx2);
        }
      }
    }
    __syncthreads();
    // ---- Phase E: gates + hidden update + publish tagged h word ----
    {
      float rr = sigm(gx0 + gh_lds[b][jj]);
      float zz = sigm(gx1 + gh_lds[b][16 + jj]);
      float nn = tanhf(gx2 + rr * gh_lds[b][32 + jj]);
      float h = (1.f - zz) * nn + zz * h_prev;
      h_prev = h;
      hnew_lds[b][jj] = h;
      unsigned short hh = f2bf(h);
      unsigned short hl = f2bf(h - bf2f(hh));
      unsigned int pay = ((unsigned int)hh << 16) | (unsigned int)hl;
      __hip_atomic_store(&hbuf[((t + 1) & 1) * 16384 + b * 512 + j0 + jj],
                         ((unsigned long long)(t + 1) << 32) | pay,
                         __ATOMIC_RELAXED, __HIP_MEMORY_SCOPE_AGENT);
    }
    __syncthreads();
    // ---- Phase F: out-projection partials (strided: 544 items, 512 threads) ----
    for (int i = tid; i < 544; i += 512) {
      int bo = i / 17, k = i - bo * 17;
      const float* owr = ow + k * 512 + j0;
      float s = 0.f;
#pragma unroll
      for (int j = 0; j < 16; j++) s += hnew_lds[bo][j] * owr[j];
      pout[((t * 32 + g) * 32 + bo) * 17 + k] = s;
    }
  }
}

// ---------------- K5: reduce pout over wgs + bias -> d_out ----------------------
__global__ __launch_bounds__(256) void k_fin(
    const float* __restrict__ pout, const float* __restrict__ ob,
    float* __restrict__ d_out) {
  int i = blockIdx.x * 256 + threadIdx.x;
  if (i >= 34816) return;
  int k = i % 17;
  int bt = i / 17;
  int b = bt >> 6, t = bt & 63;
  float s = ob[k];
#pragma unroll 8
  for (int g = 0; g < 32; g++) s += pout[((t * 32 + g) * 32 + b) * 17 + k];
  d_out[i] = s;
}

// ---------------- launch ----------------
extern "C" void kernel_launch(void* const* d_in, const int* in_sizes, int n_in,
                              void* d_out, int out_size, void* d_ws, size_t ws_size,
                              hipStream_t stream) {
  (void)in_sizes; (void)n_in; (void)out_size; (void)ws_size;
  const float* x   = (const float*)d_in[0];
  const float* cw  = (const float*)d_in[2];
  const float* kw  = (const float*)d_in[3];
  const float* bw  = (const float*)d_in[4];
  const float* wih = (const float*)d_in[5];
  const float* whh = (const float*)d_in[6];
  const float* ow  = (const float*)d_in[7];
  const float* ob  = (const float*)d_in[8];
  float* out = (float*)d_out;
  char* ws = (char*)d_ws;

  unsigned short* ctx_hi = (unsigned short*)(ws);
  unsigned short* ctx_lo = (unsigned short*)(ws + 33554432);
  unsigned short* wih_hi = (unsigned short*)(ws + 67108864);
  unsigned short* wih_lo = (unsigned short*)(ws + 92274688);
  unsigned short* whh_hi = (unsigned short*)(ws + 117440512);
  unsigned short* whh_lo = (unsigned short*)(ws + 119013376);
  float*          ctxW   = (float*)(ws + 120586240);  // [32][1536][64]
  unsigned long long* hbuf = (unsigned long long*)(ws + 133169152);  // [2][32][512]
  float*          pout   = (float*)(ws);              // overlay ctx_hi (dead after k_gemm)

  k_prep<<<49152, 256, 0, stream>>>(wih, whh, wih_hi, wih_lo, whh_hi, whh_lo, hbuf);
  k_conv<<<2048, 128, 0, stream>>>(x, cw, ctx_hi, ctx_lo);
  k_gemm<<<dim3(16, 12), 256, 0, stream>>>(ctx_hi, ctx_lo, wih_hi, wih_lo, ctxW);
  k_scan<<<NWG, 512, 0, stream>>>(ctxW, whh_hi, whh_lo, kw, bw, ow,
                                  hbuf, pout, out);
  k_fin<<<136, 256, 0, stream>>>(pout, ob, out);
}